// Round 18
// baseline (86.547 us; speedup 1.0000x reference)
//
#include <hip/hip_runtime.h>
#include <cmath>
#include <cstdint>

typedef __attribute__((ext_vector_type(8))) short short8;
typedef __attribute__((ext_vector_type(4))) float f32x4;
typedef __attribute__((ext_vector_type(2))) unsigned int u32x2;

struct Lams { float v[8]; };

#define NC 8
#define NB 4
#define NT 8192
#define ND 64
#define CL 128               // chunk length (rows per pass)
#define NP 4                 // passes per block
#define NCHUNK 64            // chunks per sequence
#define NKK 16               // blocks per sequence
#define NBLK (2 * NC * NB * NKK)     // 1024 blocks (= resident capacity)
#define NSLOT (2 * NC * NB * NCHUNK) // 4096 chunk slots
#define NWAVE 8              // waves per block
#define WR 16                // rows per wave per pass
#define LDH 72               // padded LDS row stride in bf16 halves (144 B)

// packed f32x2 -> bf16x2 (RNE), gfx950 v_cvt_pk_bf16_f32
__device__ __forceinline__ uint32_t pk2(float lo, float hi) {
    uint32_t r;
    asm("v_cvt_pk_bf16_f32 %0, %1, %2" : "=v"(r) : "v"(lo), "v"(hi));
    return r;
}

__device__ __forceinline__ float bf2f(unsigned short s) {
    return __builtin_bit_cast(float, (uint32_t)s << 16);
}
__device__ __forceinline__ float bflo(uint32_t u) { return bf2f((unsigned short)(u & 0xFFFFu)); }
__device__ __forceinline__ float bfhi(uint32_t u) { return bf2f((unsigned short)(u >> 16)); }

// Software-pipelined persistent schedule: 1024 resident blocks, CL=128,
// 4 passes (chunks kk+16p), DOUBLE-BUFFERED LDS. During the lookback
// window (wave 7: publish+spin+Horner) waves 0-6 stage the NEXT chunk
// into the other buffer (wave 0 also covers wave 7's rows) — the two
// dominant latencies overlap instead of serializing, and non-wave-7
// waves get work exactly where rounds 6/7 showed them idle.
// Protocol: fence-free relaxed agent atomics (r5), per-lane distinct
// flag polling (r8), cached quad-grouped Horner (r9).
// ws layout: int flags[NSLOT] @0 (16 KiB); float E[NSLOT][ND] @16KiB (1MiB).
__global__ __launch_bounds__(512, 4) void k1_fused(
    const float* __restrict__ x, const float* __restrict__ Wf,
    const float* __restrict__ bf, const float* __restrict__ Wb,
    const float* __restrict__ bb, float* __restrict__ out,
    int* __restrict__ flags, float* __restrict__ evals, Lams lams)
{
    __shared__ unsigned short xbuf[2][CL * LDH]; // double-buffered tile
    __shared__ float ends_lds[NWAVE][ND];        // per-wave 16-row ends (f32)
    __shared__ float hprev_lds[ND];              // resolved cross-chunk carry

    const int tid  = threadIdx.x;
    const int lane = tid & 63;
    const int w    = tid >> 6;          // wave 0..7

    int idx = blockIdx.x;
    const int kk  = idx & (NKK - 1); idx >>= 4;
    const int b   = idx & (NB - 1);  idx >>= 2;
    const int c   = idx & (NC - 1);  idx >>= 3;
    const int dir = idx;                // 0 fwd, 1 bwd

    const float lam = lams.v[c];
    const float* W    = (dir ? Wb : Wf) + c * ND * ND;
    const float* bias = (dir ? bb : bf) + c * ND;
    const float* xb   = x + (size_t)(c * NB + b) * NT * ND;
    float* ob = out + (size_t)dir * (size_t)(NC*NB*NT*ND)
                    + (size_t)(c * NB + b) * NT * ND;
    const int seqbase = (int)(blockIdx.x >> 4) * NCHUNK;  // slot base of seq

    const int er = lane & 15;   // row/col within 16-tile
    const int ks = lane >> 4;   // k-segment 0..3
    const int r0 = w * WR;      // this wave's rows [r0, r0+16) within tile

    // stage 16 rows [rb, rb+16) of chunk gc into xbuf[B] (f32x4 + b64)
    auto STAGE = [&](int B, int gc, int rb) {
        const int sr = lane >> 4;          // row within group of 4
        const int sc = (lane & 15) * 4;    // bf16 column
        const int tr = gc * CL + rb + sr;
        if (dir == 0) {
            const float* p = xb + (size_t)tr * ND + sc;
            #pragma unroll
            for (int q = 0; q < 4; ++q) {
                f32x4 v = *reinterpret_cast<const f32x4*>(p + (size_t)q * 4 * ND);
                u32x2 u = { pk2(v[0], v[1]), pk2(v[2], v[3]) };
                *reinterpret_cast<u32x2*>(&xbuf[B][(rb + q*4 + sr) * LDH + sc]) = u;
            }
        } else {
            const float* p = xb + (size_t)(NT-1 - tr) * ND + sc;
            #pragma unroll
            for (int q = 0; q < 4; ++q) {
                f32x4 v = *reinterpret_cast<const f32x4*>(p - (size_t)q * 4 * ND);
                u32x2 u = { pk2(v[0], v[1]), pk2(v[2], v[3]) };
                *reinterpret_cast<u32x2*>(&xbuf[B][(rb + q*4 + sr) * LDH + sc]) = u;
            }
        }
    };

    // ---- B fragments from W (L2-hot) + bias: once per block ----
    short8 bfrag[4][2];
    #pragma unroll
    for (int et = 0; et < 4; ++et) {
        const float* wr = W + (et*16 + er) * ND + ks * 8;
        #pragma unroll
        for (int kq = 0; kq < 2; ++kq) {
            f32x4 lo = *reinterpret_cast<const f32x4*>(wr + kq*32);
            f32x4 hi = *reinterpret_cast<const f32x4*>(wr + kq*32 + 4);
            union { short8 s8; uint32_t u[4]; } t;
            t.u[0] = pk2(lo[0], lo[1]); t.u[1] = pk2(lo[2], lo[3]);
            t.u[2] = pk2(hi[0], hi[1]); t.u[3] = pk2(hi[2], hi[3]);
            bfrag[et][kq] = t.s8;
        }
    }
    float bias_r[4];
    #pragma unroll
    for (int et = 0; et < 4; ++et) bias_r[et] = bias[et*16 + er];

    // lam^16 (wave-combine factor at WR=16)
    float lam16 = lam*lam; lam16*=lam16; lam16*=lam16; lam16*=lam16;

    // ---- prologue: every wave stages its own rows of chunk kk (pass 0) --
    STAGE(0, kk, r0);
    // no barrier: wave w staged exactly the rows it gates/scans next

    #pragma unroll 1
    for (int p = 0; p < NP; ++p) {
        const int P   = p & 1;
        const int g   = kk + NKK * p;   // global chunk index 0..63
        const int tr0 = g * CL;

        // ---- gate: MFMA logits + sigmoid; gate xbuf[P] in place ----
        {
            short8 afrag[2];
            afrag[0] = *reinterpret_cast<const short8*>(&xbuf[P][(r0 + er) * LDH + ks * 8]);
            afrag[1] = *reinterpret_cast<const short8*>(&xbuf[P][(r0 + er) * LDH + 32 + ks * 8]);
            #pragma unroll
            for (int et = 0; et < 4; ++et) {
                f32x4 acc = {0.f, 0.f, 0.f, 0.f};
                acc = __builtin_amdgcn_mfma_f32_16x16x32_bf16(afrag[0], bfrag[et][0], acc, 0,0,0);
                acc = __builtin_amdgcn_mfma_f32_16x16x32_bf16(afrag[1], bfrag[et][1], acc, 0,0,0);
                const int col = et*16 + er;
                float gated[4];
                #pragma unroll
                for (int r = 0; r < 4; ++r) {
                    const int rl = r0 + ks*4 + r;   // C/D: col=lane&15, row=(lane>>4)*4+r
                    float z  = acc[r] + bias_r[et];
                    float gg = __builtin_amdgcn_rcpf(1.0f + __expf(-z));
                    float xv = bf2f(xbuf[P][rl * LDH + col]);
                    gated[r] = gg * xv;
                }
                uint32_t p01 = pk2(gated[0], gated[1]);
                uint32_t p23 = pk2(gated[2], gated[3]);
                xbuf[P][(r0 + ks*4 + 0) * LDH + col] = (unsigned short)(p01 & 0xFFFF);
                xbuf[P][(r0 + ks*4 + 1) * LDH + col] = (unsigned short)(p01 >> 16);
                xbuf[P][(r0 + ks*4 + 2) * LDH + col] = (unsigned short)(p23 & 0xFFFF);
                xbuf[P][(r0 + ks*4 + 3) * LDH + col] = (unsigned short)(p23 >> 16);
            }
        }

        // ---- wave-local scan (16 rows): h in f32; stored back bf16 ----
        float hend;
        {
            float h = 0.f;
            #pragma unroll
            for (int i = 0; i < WR; ++i) {
                const int a = (r0 + i) * LDH + lane;
                float v = bf2f(xbuf[P][a]);
                h = fmaf(h, lam, v);
                xbuf[P][a] = (unsigned short)(pk2(h, h) & 0xFFFF);
            }
            ends_lds[w][lane] = h;
            hend = h;
        }
        __syncthreads();   // b1: ends_lds ready

        // ---- lookback window: wave 7 does protocol; others stage next ----
        if (w == NWAVE - 1) {
            float carryW = 0.f;
            #pragma unroll
            for (int j = 0; j < NWAVE - 1; ++j)
                carryW = fmaf(carryW, lam16, ends_lds[j][lane]);
            float E = fmaf(carryW, lam16, hend);   // local inclusive chunk end

            float Hprev = 0.f;
            if (c != 0) {
                const int slot = seqbase + g;
                __hip_atomic_store(&evals[(size_t)slot * ND + lane], E,
                                   __ATOMIC_RELAXED, __HIP_MEMORY_SCOPE_AGENT);
                asm volatile("s_waitcnt vmcnt(0)" ::: "memory");
                if (lane == 0)
                    __hip_atomic_store(&flags[slot], 1, __ATOMIC_RELAXED,
                                       __HIP_MEMORY_SCOPE_AGENT);
                if (g != 0) {
                    if (lane < g) {
                        while (__hip_atomic_load(&flags[seqbase + lane], __ATOMIC_RELAXED,
                                                 __HIP_MEMORY_SCOPE_AGENT) == 0)
                            __builtin_amdgcn_s_sleep(2);
                    }
                    asm volatile("" ::: "memory");
                    const float* eb = evals + (size_t)seqbase * ND;
                    float l1 = lam16 * lam16; l1 *= l1; l1 *= l1;  // lam^128
                    float l4 = l1 * l1; l4 *= l4;                  // lam^512
                    float P2 = 0.f;
                    int j = 0;
                    const int rem = g & 3;
                    for (; j < rem; ++j)
                        P2 = fmaf(P2, l1, eb[(size_t)j * ND + lane]);
                    for (; j < g; j += 4) {
                        float e0 = eb[(size_t)(j+0) * ND + lane];
                        float e1 = eb[(size_t)(j+1) * ND + lane];
                        float e2 = eb[(size_t)(j+2) * ND + lane];
                        float e3 = eb[(size_t)(j+3) * ND + lane];
                        float t = fmaf(fmaf(fmaf(e0, l1, e1), l1, e2), l1, e3);
                        P2 = fmaf(P2, l4, t);
                    }
                    Hprev = P2;
                }
            }
            hprev_lds[lane] = Hprev;
        } else if (p + 1 < NP) {
            STAGE(P ^ 1, kk + NKK * (p + 1), r0);          // own next rows
            if (w == 0)
                STAGE(P ^ 1, kk + NKK * (p + 1), 7 * WR);  // cover wave 7
        }
        __syncthreads();   // b2: hprev ready; next-buffer staged

        // ---- carry per d-subgroup, vectorized final write (f32x4) ----
        {
            const int sr = lane >> 4;        // row within group of 4
            const int dg = lane & 15;        // d-group (4 consecutive d)
            float carry4[4];
            #pragma unroll
            for (int j2 = 0; j2 < 4; ++j2) {
                const int d = dg*4 + j2;
                float cy = 0.f, pw = 1.f;
                for (int j = 0; j < w; ++j) {
                    cy = fmaf(cy, lam16, ends_lds[j][d]);
                    pw *= lam16;
                }
                carry4[j2] = fmaf(pw, hprev_lds[d], cy);
            }
            const float lam2 = lam * lam, lam4 = lam2 * lam2;
            float f = lam;
            for (int j = 0; j < sr; ++j) f *= lam;   // lam^(sr+1)
            if (dir == 0) {
                float* pp = ob + (size_t)(tr0 + r0 + sr) * ND + dg*4;
                #pragma unroll
                for (int q = 0; q < 4; ++q) {
                    u32x2 hv = *reinterpret_cast<const u32x2*>(
                        &xbuf[P][(r0 + q*4 + sr) * LDH + dg*4]);
                    f32x4 o;
                    o[0] = fmaf(f, carry4[0], bflo(hv[0]));
                    o[1] = fmaf(f, carry4[1], bfhi(hv[0]));
                    o[2] = fmaf(f, carry4[2], bflo(hv[1]));
                    o[3] = fmaf(f, carry4[3], bfhi(hv[1]));
                    *reinterpret_cast<f32x4*>(pp + (size_t)q * 4 * ND) = o;
                    f *= lam4;
                }
            } else {
                float* pp = ob + (size_t)(NT-1 - (tr0 + r0 + sr)) * ND + dg*4;
                #pragma unroll
                for (int q = 0; q < 4; ++q) {
                    u32x2 hv = *reinterpret_cast<const u32x2*>(
                        &xbuf[P][(r0 + q*4 + sr) * LDH + dg*4]);
                    f32x4 o;
                    o[0] = fmaf(f, carry4[0], bflo(hv[0]));
                    o[1] = fmaf(f, carry4[1], bfhi(hv[0]));
                    o[2] = fmaf(f, carry4[2], bflo(hv[1]));
                    o[3] = fmaf(f, carry4[3], bfhi(hv[1]));
                    *reinterpret_cast<f32x4*>(pp - (size_t)q * 4 * ND) = o;
                    f *= lam4;
                }
            }
        }
        __syncthreads();   // b3: ends_lds/hprev WAR safety for next pass
    }
}

extern "C" void kernel_launch(void* const* d_in, const int* in_sizes, int n_in,
                              void* d_out, int out_size, void* d_ws, size_t ws_size,
                              hipStream_t stream)
{
    const float* x  = (const float*)d_in[0];
    const float* Wf = (const float*)d_in[1];
    const float* bf = (const float*)d_in[2];
    const float* Wb = (const float*)d_in[3];
    const float* bb = (const float*)d_in[4];
    float* out = (float*)d_out;

    int*   flags = (int*)d_ws;                         // NSLOT ints (16 KiB)
    float* evals = (float*)((char*)d_ws + 16384);      // NSLOT*ND floats (1 MiB)

    Lams lams;
    const double delta = 13.0 / 7.0;   // log2(8192)/(C-1)
    for (int c = 0; c < 8; ++c)
        lams.v[c] = (float)(1.0 - pow(2.0, -(double)c * delta));

    // reset flags every launch (graph-replay safe, on-stream)
    hipMemsetAsync(flags, 0, NSLOT * 4, stream);

    dim3 grid(NBLK);   // 1024 blocks: (dir,c,b,kk), kk fastest — all resident
    k1_fused<<<grid, 512, 0, stream>>>(x, Wf, bf, Wb, bb, out, flags, evals, lams);
}

// Round 19
// 72.990 us; speedup vs baseline: 1.1857x; 1.1857x over previous
//
#include <hip/hip_runtime.h>
#include <cmath>
#include <cstdint>

typedef __attribute__((ext_vector_type(8))) short short8;
typedef __attribute__((ext_vector_type(4))) float f32x4;
typedef __attribute__((ext_vector_type(2))) unsigned int u32x2;

struct Lams { float v[8]; };

#define NC 8
#define NB 4
#define NT 8192
#define ND 64
#define CL 256               // chunk length (rows per pass)
#define NP 2                 // passes per block
#define NCHUNK 32            // chunks per sequence
#define NKK 16               // blocks per sequence
#define NBLK (2 * NC * NB * NKK)     // 1024 blocks (= resident capacity)
#define NSLOT (2 * NC * NB * NCHUNK) // 2048 chunk slots
#define NWAVE 8              // waves per block
#define LDH 68               // padded LDS row stride in bf16 halves (136 B)

// packed f32x2 -> bf16x2 (RNE), gfx950 v_cvt_pk_bf16_f32
__device__ __forceinline__ uint32_t pk2(float lo, float hi) {
    uint32_t r;
    asm("v_cvt_pk_bf16_f32 %0, %1, %2" : "=v"(r) : "v"(lo), "v"(hi));
    return r;
}

__device__ __forceinline__ float bf2f(unsigned short s) {
    return __builtin_bit_cast(float, (uint32_t)s << 16);
}
__device__ __forceinline__ float bflo(uint32_t u) { return bf2f((unsigned short)(u & 0xFFFFu)); }
__device__ __forceinline__ float bfhi(uint32_t u) { return bf2f((unsigned short)(u >> 16)); }

// r17 base (70.3us) with the end-of-pass barrier DELETED: every xbuf
// access is wave-private (each wave stages/gates/scans/writes only its
// own 32 rows), so only ends_lds/hprev_lds need cross-wave WAR safety —
// double-buffer those (tiny) instead of barriering. Epilogue stores now
// drain lazily under the next pass's stage+gate+scan instead of stalling
// all 8 waves at a vmcnt(0) drain. 4 barriers total (was 6). LDH 72->68
// keeps LDS <= 40KB -> 4 blocks/CU. Protocol identical to r17.
// ws layout: int flags[NSLOT] @0 (8 KiB); float E[NSLOT][ND] @16KiB.
__global__ __launch_bounds__(512, 4) void k1_fused(
    const float* __restrict__ x, const float* __restrict__ Wf,
    const float* __restrict__ bf, const float* __restrict__ Wb,
    const float* __restrict__ bb, float* __restrict__ out,
    int* __restrict__ flags, float* __restrict__ evals, Lams lams)
{
    __shared__ unsigned short xbuf[CL * LDH];   // x -> gated -> h (bf16)
    __shared__ float ends_lds[2][NWAVE][ND];    // per-wave ends, dbuf (f32)
    __shared__ float hprev_lds[2][ND];          // cross-chunk carry, dbuf

    const int tid  = threadIdx.x;
    const int lane = tid & 63;
    const int w    = tid >> 6;          // wave 0..7

    int idx = blockIdx.x;
    const int kk  = idx & (NKK - 1); idx >>= 4;
    const int b   = idx & (NB - 1);  idx >>= 2;
    const int c   = idx & (NC - 1);  idx >>= 3;
    const int dir = idx;                // 0 fwd, 1 bwd

    const float lam = lams.v[c];
    const float* W    = (dir ? Wb : Wf) + c * ND * ND;
    const float* bias = (dir ? bb : bf) + c * ND;
    const float* xb   = x + (size_t)(c * NB + b) * NT * ND;
    float* ob = out + (size_t)dir * (size_t)(NC*NB*NT*ND)
                    + (size_t)(c * NB + b) * NT * ND;
    const int seqbase = (int)(blockIdx.x >> 4) * NCHUNK;  // slot base of seq

    const int er = lane & 15;   // row/col within 16-tile
    const int ks = lane >> 4;   // k-segment 0..3
    const int r0 = w * 32;      // this wave's rows [r0, r0+32) within tile

    // stage this wave's 32 rows of chunk gc into xbuf (f32x4 + b64)
    auto STAGE = [&](int gc) {
        const int sr = lane >> 4;          // row within group of 4
        const int sc = (lane & 15) * 4;    // bf16 column
        const int tr = gc * CL + r0 + sr;
        if (dir == 0) {
            const float* p = xb + (size_t)tr * ND + sc;
            #pragma unroll
            for (int q = 0; q < 8; ++q) {
                f32x4 v = *reinterpret_cast<const f32x4*>(p + (size_t)q * 4 * ND);
                u32x2 u = { pk2(v[0], v[1]), pk2(v[2], v[3]) };
                *reinterpret_cast<u32x2*>(&xbuf[(r0 + q*4 + sr) * LDH + sc]) = u;
            }
        } else {
            const float* p = xb + (size_t)(NT-1 - tr) * ND + sc;
            #pragma unroll
            for (int q = 0; q < 8; ++q) {
                f32x4 v = *reinterpret_cast<const f32x4*>(p - (size_t)q * 4 * ND);
                u32x2 u = { pk2(v[0], v[1]), pk2(v[2], v[3]) };
                *reinterpret_cast<u32x2*>(&xbuf[(r0 + q*4 + sr) * LDH + sc]) = u;
            }
        }
    };

    // ---- B fragments from W (L2-hot) + bias: once per block ----
    short8 bfrag[4][2];
    #pragma unroll
    for (int et = 0; et < 4; ++et) {
        const float* wr = W + (et*16 + er) * ND + ks * 8;
        #pragma unroll
        for (int kq = 0; kq < 2; ++kq) {
            f32x4 lo = *reinterpret_cast<const f32x4*>(wr + kq*32);
            f32x4 hi = *reinterpret_cast<const f32x4*>(wr + kq*32 + 4);
            union { short8 s8; uint32_t u[4]; } t;
            t.u[0] = pk2(lo[0], lo[1]); t.u[1] = pk2(lo[2], lo[3]);
            t.u[2] = pk2(hi[0], hi[1]); t.u[3] = pk2(hi[2], hi[3]);
            bfrag[et][kq] = t.s8;
        }
    }
    float bias_r[4];
    #pragma unroll
    for (int et = 0; et < 4; ++et) bias_r[et] = bias[et*16 + er];

    float lam32 = lam*lam; lam32*=lam32; lam32*=lam32; lam32*=lam32; lam32*=lam32;

    // ---- prologue: stage pass-0 chunk (own rows; no barrier needed) ----
    STAGE(kk);

    #pragma unroll 1
    for (int p = 0; p < NP; ++p) {
        const int P   = p & 1;             // ends/hprev buffer select
        const int g   = kk + NKK * p;      // global chunk index 0..31
        const int tr0 = g * CL;

        // ---- MFMA logits + sigmoid epilogue; gate xbuf in place ----
        #pragma unroll
        for (int u = 0; u < 2; ++u) {
            const int rl0 = r0 + u*16;
            short8 afrag[2];
            afrag[0] = *reinterpret_cast<const short8*>(&xbuf[(rl0 + er) * LDH + ks * 8]);
            afrag[1] = *reinterpret_cast<const short8*>(&xbuf[(rl0 + er) * LDH + 32 + ks * 8]);
            #pragma unroll
            for (int et = 0; et < 4; ++et) {
                f32x4 acc = {0.f, 0.f, 0.f, 0.f};
                acc = __builtin_amdgcn_mfma_f32_16x16x32_bf16(afrag[0], bfrag[et][0], acc, 0,0,0);
                acc = __builtin_amdgcn_mfma_f32_16x16x32_bf16(afrag[1], bfrag[et][1], acc, 0,0,0);
                const int col = et*16 + er;
                float gated[4];
                #pragma unroll
                for (int r = 0; r < 4; ++r) {
                    const int rl = rl0 + ks*4 + r;   // C/D: col=lane&15, row=(lane>>4)*4+r
                    float z  = acc[r] + bias_r[et];
                    float gg = __builtin_amdgcn_rcpf(1.0f + __expf(-z));
                    float xv = bf2f(xbuf[rl * LDH + col]);
                    gated[r] = gg * xv;
                }
                uint32_t p01 = pk2(gated[0], gated[1]);
                uint32_t p23 = pk2(gated[2], gated[3]);
                xbuf[(rl0 + ks*4 + 0) * LDH + col] = (unsigned short)(p01 & 0xFFFF);
                xbuf[(rl0 + ks*4 + 1) * LDH + col] = (unsigned short)(p01 >> 16);
                xbuf[(rl0 + ks*4 + 2) * LDH + col] = (unsigned short)(p23 & 0xFFFF);
                xbuf[(rl0 + ks*4 + 3) * LDH + col] = (unsigned short)(p23 >> 16);
            }
        }

        // ---- wave-local scan: h in f32 reg; stored back as bf16 ----
        {
            float h = 0.f;
            #pragma unroll
            for (int i = 0; i < 32; ++i) {
                const int a = (r0 + i) * LDH + lane;
                float v = bf2f(xbuf[a]);
                h = fmaf(h, lam, v);
                xbuf[a] = (unsigned short)(pk2(h, h) & 0xFFFF);
            }
            ends_lds[P][w][lane] = h;   // f32 chain for E/carry precision
        }
        __syncthreads();   // b1: ends ready

        // ---- wave 7: publish chunk end, decoupled lookback ----
        if (w == NWAVE - 1) {
            float carryW = 0.f;
            #pragma unroll
            for (int j = 0; j < NWAVE - 1; ++j)
                carryW = fmaf(carryW, lam32, ends_lds[P][j][lane]);
            float E = fmaf(carryW, lam32, ends_lds[P][NWAVE-1][lane]);

            float Hprev = 0.f;
            if (c != 0) {
                const int slot = seqbase + g;
                // publish E via relaxed agent atomics (no fence: r5 lesson)
                __hip_atomic_store(&evals[(size_t)slot * ND + lane], E,
                                   __ATOMIC_RELAXED, __HIP_MEMORY_SCOPE_AGENT);
                asm volatile("s_waitcnt vmcnt(0)" ::: "memory");
                if (lane == 0)
                    __hip_atomic_store(&flags[slot], 1, __ATOMIC_RELAXED,
                                       __HIP_MEMORY_SCOPE_AGENT);
                if (g != 0) {
                    // parallel spin: one predecessor flag per lane (distinct
                    // addresses; r8 lesson: never same-address multi-lane)
                    if (lane < g) {
                        while (__hip_atomic_load(&flags[seqbase + lane], __ATOMIC_RELAXED,
                                                 __HIP_MEMORY_SCOPE_AGENT) == 0)
                            __builtin_amdgcn_s_sleep(2);
                    }
                    asm volatile("" ::: "memory");
                    // quad-grouped Horner, plain cached loads (write-once data)
                    const float* eb = evals + (size_t)seqbase * ND;
                    float l1 = lam32*lam32; l1 *= l1; l1 *= l1;   // lam^256
                    float l4 = l1 * l1; l4 *= l4;                 // lam^1024
                    float Ph = 0.f;
                    int j = 0;
                    const int rem = g & 3;
                    for (; j < rem; ++j)
                        Ph = fmaf(Ph, l1, eb[(size_t)j * ND + lane]);
                    for (; j < g; j += 4) {
                        float e0 = eb[(size_t)(j+0) * ND + lane];
                        float e1 = eb[(size_t)(j+1) * ND + lane];
                        float e2 = eb[(size_t)(j+2) * ND + lane];
                        float e3 = eb[(size_t)(j+3) * ND + lane];
                        float t = fmaf(fmaf(fmaf(e0, l1, e1), l1, e2), l1, e3);
                        Ph = fmaf(Ph, l4, t);
                    }
                    Hprev = Ph;
                }
            }
            hprev_lds[P][lane] = Hprev;
        }
        __syncthreads();   // b2: hprev ready

        // ---- carry per d-subgroup, vectorized final write (f32x4) ----
        {
            const int sr = lane >> 4;        // row within group of 4
            const int dg = lane & 15;        // d-group (4 consecutive d)
            float carry4[4];
            #pragma unroll
            for (int j2 = 0; j2 < 4; ++j2) {
                const int d = dg*4 + j2;
                float cy = 0.f, pw = 1.f;
                for (int j = 0; j < w; ++j) {
                    cy = fmaf(cy, lam32, ends_lds[P][j][d]);
                    pw *= lam32;
                }
                carry4[j2] = fmaf(pw, hprev_lds[P][d], cy);
            }
            const float lam2 = lam * lam, lam4 = lam2 * lam2;
            float f = lam;
            for (int j = 0; j < sr; ++j) f *= lam;   // lam^(sr+1)
            if (dir == 0) {
                float* pp = ob + (size_t)(tr0 + r0 + sr) * ND + dg*4;
                #pragma unroll
                for (int q = 0; q < 8; ++q) {
                    u32x2 hv = *reinterpret_cast<const u32x2*>(
                        &xbuf[(r0 + q*4 + sr) * LDH + dg*4]);
                    f32x4 o;
                    o[0] = fmaf(f, carry4[0], bflo(hv[0]));
                    o[1] = fmaf(f, carry4[1], bfhi(hv[0]));
                    o[2] = fmaf(f, carry4[2], bflo(hv[1]));
                    o[3] = fmaf(f, carry4[3], bfhi(hv[1]));
                    *reinterpret_cast<f32x4*>(pp + (size_t)q * 4 * ND) = o;
                    f *= lam4;
                }
            } else {
                float* pp = ob + (size_t)(NT-1 - (tr0 + r0 + sr)) * ND + dg*4;
                #pragma unroll
                for (int q = 0; q < 8; ++q) {
                    u32x2 hv = *reinterpret_cast<const u32x2*>(
                        &xbuf[(r0 + q*4 + sr) * LDH + dg*4]);
                    f32x4 o;
                    o[0] = fmaf(f, carry4[0], bflo(hv[0]));
                    o[1] = fmaf(f, carry4[1], bfhi(hv[0]));
                    o[2] = fmaf(f, carry4[2], bflo(hv[1]));
                    o[3] = fmaf(f, carry4[3], bfhi(hv[1]));
                    *reinterpret_cast<f32x4*>(pp - (size_t)q * 4 * ND) = o;
                    f *= lam4;
                }
            }
        }

        // ---- stage next pass's chunk (own rows; epilogue reads done) ----
        if (p + 1 < NP) {
            // compiler-only ordering: keep staging LDS writes after the
            // epilogue's LDS reads of the same rows (hardware ds ops are
            // in-order per wave; out-stores/x-loads stay independent via
            // __restrict__ and overlap in flight)
            asm volatile("" ::: "memory");
            STAGE(kk + NKK * (p + 1));
        }
        // NO end-of-pass barrier: xbuf is wave-private; ends/hprev are
        // double-buffered; epilogue stores drain under the next pass.
    }
}

extern "C" void kernel_launch(void* const* d_in, const int* in_sizes, int n_in,
                              void* d_out, int out_size, void* d_ws, size_t ws_size,
                              hipStream_t stream)
{
    const float* x  = (const float*)d_in[0];
    const float* Wf = (const float*)d_in[1];
    const float* bf = (const float*)d_in[2];
    const float* Wb = (const float*)d_in[3];
    const float* bb = (const float*)d_in[4];
    float* out = (float*)d_out;

    int*   flags = (int*)d_ws;                         // NSLOT ints (8 KiB)
    float* evals = (float*)((char*)d_ws + 16384);      // NSLOT*ND floats (512 KiB)

    Lams lams;
    const double delta = 13.0 / 7.0;   // log2(8192)/(C-1)
    for (int c = 0; c < 8; ++c)
        lams.v[c] = (float)(1.0 - pow(2.0, -(double)c * delta));

    // reset flags every launch (graph-replay safe, on-stream)
    hipMemsetAsync(flags, 0, NSLOT * 4, stream);

    dim3 grid(NBLK);   // 1024 blocks: (dir,c,b,kk), kk fastest — all resident
    k1_fused<<<grid, 512, 0, stream>>>(x, Wf, bf, Wb, bb, out, flags, evals, lams);
}

// Round 20
// 69.992 us; speedup vs baseline: 1.2365x; 1.0428x over previous
//
#include <hip/hip_runtime.h>
#include <cmath>
#include <cstdint>

typedef __attribute__((ext_vector_type(8))) short short8;
typedef __attribute__((ext_vector_type(4))) float f32x4;
typedef __attribute__((ext_vector_type(2))) unsigned int u32x2;

struct Lams { float v[8]; };

#define NC 8
#define NB 4
#define NT 8192
#define ND 64
#define CL 256               // chunk length (rows per pass)
#define NCHUNK 32            // chunks per sequence
#define NKK 16               // chunk-pairs per sequence (blocks per seq)
#define NBLK (2 * NC * NB * NKK)     // 1024 blocks (= resident capacity)
#define NSLOT (2 * NC * NB * NCHUNK) // 2048 chunk slots
#define NWAVE 8              // waves per block
#define LDH 72               // padded LDS row stride in bf16 halves (144 B)

// packed f32x2 -> bf16x2 (RNE), gfx950 v_cvt_pk_bf16_f32
__device__ __forceinline__ uint32_t pk2(float lo, float hi) {
    uint32_t r;
    asm("v_cvt_pk_bf16_f32 %0, %1, %2" : "=v"(r) : "v"(lo), "v"(hi));
    return r;
}

__device__ __forceinline__ float bf2f(unsigned short s) {
    return __builtin_bit_cast(float, (uint32_t)s << 16);
}
__device__ __forceinline__ float bflo(uint32_t u) { return bf2f((unsigned short)(u & 0xFFFFu)); }
__device__ __forceinline__ float bfhi(uint32_t u) { return bf2f((unsigned short)(u >> 16)); }

// FINAL (round-17 configuration, best measured: 70.3us, absmax 1.0).
// Persistent single-generation schedule: 1024 resident blocks (4/CU x 256
// CU), each handling chunks kk (pass A) and kk+16 (pass B) of its
// (dir,c,b) sequence — out-of-order pairing keeps all lookback
// dependencies within the concurrently-running pass. Fence-free decoupled
// lookback: relaxed agent atomics only (r5: acquire/release fences cause
// per-XCD L2 invalidate storms, 3-30x slowdowns), per-lane distinct-
// address flag polling (r8: same-address multi-lane atomic polls
// serialize at the coherence point), cached quad-grouped Horner (r9:
// evals is write-once data). Local phase: row-major bf16 LDS tile
// (wave-private rows -> no staging/gate barriers), MFMA 16x16x32 logits,
// in-place sigmoid gate, f32-register scan chain with bf16 h store-back,
// f32x4 vectorized staging loads and epilogue stores.
// Explored-and-flat: occupancy 36->74%, VALU halved, LDS ops quartered,
// VMEM insts quartered, protocol halved, barrier deletion, pipelining —
// all within noise of 70us; the residual is exposed memory latency on the
// serialized phase chain (~2.2x the 32us HBM floor for 194 MB).
// ws layout: int flags[NSLOT] @0 (8 KiB); float E[NSLOT][ND] @16KiB.
__global__ __launch_bounds__(512, 4) void k1_fused(
    const float* __restrict__ x, const float* __restrict__ Wf,
    const float* __restrict__ bf, const float* __restrict__ Wb,
    const float* __restrict__ bb, float* __restrict__ out,
    int* __restrict__ flags, float* __restrict__ evals, Lams lams)
{
    __shared__ unsigned short xbuf[CL * LDH];   // x -> gated -> h (bf16)
    __shared__ float ends_lds[NWAVE][ND];       // per-wave sub-chunk ends (f32)
    __shared__ float hprev_lds[ND];             // resolved cross-chunk carry

    const int tid  = threadIdx.x;
    const int lane = tid & 63;
    const int w    = tid >> 6;          // wave 0..7

    int idx = blockIdx.x;
    const int kk  = idx & (NKK - 1); idx >>= 4;
    const int b   = idx & (NB - 1);  idx >>= 2;
    const int c   = idx & (NC - 1);  idx >>= 3;
    const int dir = idx;                // 0 fwd, 1 bwd

    const float lam = lams.v[c];
    const float* W    = (dir ? Wb : Wf) + c * ND * ND;
    const float* bias = (dir ? bb : bf) + c * ND;
    const float* xb   = x + (size_t)(c * NB + b) * NT * ND;
    float* ob = out + (size_t)dir * (size_t)(NC*NB*NT*ND)
                    + (size_t)(c * NB + b) * NT * ND;
    const int seqbase = (int)(blockIdx.x >> 4) * NCHUNK;  // slot base of seq

    const int er = lane & 15;   // row/col within 16-tile
    const int ks = lane >> 4;   // k-segment 0..3
    const int r0 = w * 32;      // this wave's rows [r0, r0+32) within tile

    // ---- B fragments from W (L2-hot) + bias: once per block ----
    short8 bfrag[4][2];
    #pragma unroll
    for (int et = 0; et < 4; ++et) {
        const float* wr = W + (et*16 + er) * ND + ks * 8;
        #pragma unroll
        for (int kq = 0; kq < 2; ++kq) {
            f32x4 lo = *reinterpret_cast<const f32x4*>(wr + kq*32);
            f32x4 hi = *reinterpret_cast<const f32x4*>(wr + kq*32 + 4);
            union { short8 s8; uint32_t u[4]; } t;
            t.u[0] = pk2(lo[0], lo[1]); t.u[1] = pk2(lo[2], lo[3]);
            t.u[2] = pk2(hi[0], hi[1]); t.u[3] = pk2(hi[2], hi[3]);
            bfrag[et][kq] = t.s8;
        }
    }
    float bias_r[4];
    #pragma unroll
    for (int et = 0; et < 4; ++et) bias_r[et] = bias[et*16 + er];

    float lam32 = lam*lam; lam32*=lam32; lam32*=lam32; lam32*=lam32; lam32*=lam32;

    #pragma unroll 1
    for (int pass = 0; pass < 2; ++pass) {
        const int g   = kk + NKK * pass;   // global chunk index 0..31
        const int tr0 = g * CL;

        // ---- stage x rows [r0,r0+32) -> xbuf, f32x4 loads ----
        {
            const int sr = lane >> 4;          // row within group of 4
            const int sc = (lane & 15) * 4;    // bf16 column
            if (dir == 0) {
                const float* p = xb + (size_t)(tr0 + r0 + sr) * ND + sc;
                #pragma unroll
                for (int q = 0; q < 8; ++q) {
                    f32x4 v = *reinterpret_cast<const f32x4*>(p + (size_t)q * 4 * ND);
                    u32x2 u = { pk2(v[0], v[1]), pk2(v[2], v[3]) };
                    *reinterpret_cast<u32x2*>(&xbuf[(r0 + q*4 + sr) * LDH + sc]) = u;
                }
            } else {
                const float* p = xb + (size_t)(NT-1 - (tr0 + r0 + sr)) * ND + sc;
                #pragma unroll
                for (int q = 0; q < 8; ++q) {
                    f32x4 v = *reinterpret_cast<const f32x4*>(p - (size_t)q * 4 * ND);
                    u32x2 u = { pk2(v[0], v[1]), pk2(v[2], v[3]) };
                    *reinterpret_cast<u32x2*>(&xbuf[(r0 + q*4 + sr) * LDH + sc]) = u;
                }
            }
        }
        // no barrier: wave w staged exactly the rows it gates/scans next

        // ---- MFMA logits + sigmoid epilogue; gate xbuf in place ----
        #pragma unroll
        for (int u = 0; u < 2; ++u) {
            const int rl0 = r0 + u*16;
            short8 afrag[2];
            afrag[0] = *reinterpret_cast<const short8*>(&xbuf[(rl0 + er) * LDH + ks * 8]);
            afrag[1] = *reinterpret_cast<const short8*>(&xbuf[(rl0 + er) * LDH + 32 + ks * 8]);
            #pragma unroll
            for (int et = 0; et < 4; ++et) {
                f32x4 acc = {0.f, 0.f, 0.f, 0.f};
                acc = __builtin_amdgcn_mfma_f32_16x16x32_bf16(afrag[0], bfrag[et][0], acc, 0,0,0);
                acc = __builtin_amdgcn_mfma_f32_16x16x32_bf16(afrag[1], bfrag[et][1], acc, 0,0,0);
                const int col = et*16 + er;
                float gated[4];
                #pragma unroll
                for (int r = 0; r < 4; ++r) {
                    const int rl = rl0 + ks*4 + r;   // C/D: col=lane&15, row=(lane>>4)*4+r
                    float z  = acc[r] + bias_r[et];
                    float gg = __builtin_amdgcn_rcpf(1.0f + __expf(-z));
                    float xv = bf2f(xbuf[rl * LDH + col]);
                    gated[r] = gg * xv;
                }
                uint32_t p01 = pk2(gated[0], gated[1]);
                uint32_t p23 = pk2(gated[2], gated[3]);
                xbuf[(rl0 + ks*4 + 0) * LDH + col] = (unsigned short)(p01 & 0xFFFF);
                xbuf[(rl0 + ks*4 + 1) * LDH + col] = (unsigned short)(p01 >> 16);
                xbuf[(rl0 + ks*4 + 2) * LDH + col] = (unsigned short)(p23 & 0xFFFF);
                xbuf[(rl0 + ks*4 + 3) * LDH + col] = (unsigned short)(p23 >> 16);
            }
        }
        // no barrier: wave w only ever touched its own rows [r0, r0+32)

        // ---- wave-local scan: h in f32 reg; stored back as bf16 ----
        {
            float h = 0.f;
            #pragma unroll
            for (int i = 0; i < 32; ++i) {
                const int a = (r0 + i) * LDH + lane;
                float v = bf2f(xbuf[a]);
                h = fmaf(h, lam, v);
                xbuf[a] = (unsigned short)(pk2(h, h) & 0xFFFF);
            }
            ends_lds[w][lane] = h;   // f32 chain for E/carry precision
        }
        __syncthreads();

        // ---- wave 7: publish chunk end, decoupled lookback ----
        if (w == NWAVE - 1) {
            float carryW = 0.f;
            #pragma unroll
            for (int j = 0; j < NWAVE - 1; ++j)
                carryW = fmaf(carryW, lam32, ends_lds[j][lane]);
            float E = fmaf(carryW, lam32, ends_lds[NWAVE-1][lane]);  // local end

            float Hprev = 0.f;
            if (c != 0) {
                const int slot = seqbase + g;
                // publish E via relaxed agent atomics (no fence: r5 lesson)
                __hip_atomic_store(&evals[(size_t)slot * ND + lane], E,
                                   __ATOMIC_RELAXED, __HIP_MEMORY_SCOPE_AGENT);
                asm volatile("s_waitcnt vmcnt(0)" ::: "memory");
                if (lane == 0)
                    __hip_atomic_store(&flags[slot], 1, __ATOMIC_RELAXED,
                                       __HIP_MEMORY_SCOPE_AGENT);
                if (g != 0) {
                    // parallel spin: one predecessor flag per lane (distinct
                    // addresses; r8 lesson: never same-address multi-lane)
                    if (lane < g) {
                        while (__hip_atomic_load(&flags[seqbase + lane], __ATOMIC_RELAXED,
                                                 __HIP_MEMORY_SCOPE_AGENT) == 0)
                            __builtin_amdgcn_s_sleep(2);
                    }
                    asm volatile("" ::: "memory");
                    // quad-grouped Horner, plain cached loads (write-once data)
                    const float* eb = evals + (size_t)seqbase * ND;
                    float l1 = lam32*lam32; l1 *= l1; l1 *= l1;   // lam^256
                    float l4 = l1 * l1; l4 *= l4;                 // lam^1024
                    float P = 0.f;
                    int j = 0;
                    const int rem = g & 3;
                    for (; j < rem; ++j)
                        P = fmaf(P, l1, eb[(size_t)j * ND + lane]);
                    for (; j < g; j += 4) {
                        float e0 = eb[(size_t)(j+0) * ND + lane];
                        float e1 = eb[(size_t)(j+1) * ND + lane];
                        float e2 = eb[(size_t)(j+2) * ND + lane];
                        float e3 = eb[(size_t)(j+3) * ND + lane];
                        float t = fmaf(fmaf(fmaf(e0, l1, e1), l1, e2), l1, e3);
                        P = fmaf(P, l4, t);
                    }
                    Hprev = P;
                }
            }
            hprev_lds[lane] = Hprev;
        }
        __syncthreads();

        // ---- carry per d-subgroup, vectorized final write (f32x4) ----
        {
            const int sr = lane >> 4;        // row within group of 4
            const int dg = lane & 15;        // d-group (4 consecutive d)
            float carry4[4];
            #pragma unroll
            for (int j2 = 0; j2 < 4; ++j2) {
                const int d = dg*4 + j2;
                float cy = 0.f, pw = 1.f;
                for (int j = 0; j < w; ++j) {
                    cy = fmaf(cy, lam32, ends_lds[j][d]);
                    pw *= lam32;
                }
                carry4[j2] = fmaf(pw, hprev_lds[d], cy);
            }
            const float lam2 = lam * lam, lam4 = lam2 * lam2;
            float f = lam;
            for (int j = 0; j < sr; ++j) f *= lam;   // lam^(sr+1)
            if (dir == 0) {
                float* p = ob + (size_t)(tr0 + r0 + sr) * ND + dg*4;
                #pragma unroll
                for (int q = 0; q < 8; ++q) {
                    u32x2 hv = *reinterpret_cast<const u32x2*>(
                        &xbuf[(r0 + q*4 + sr) * LDH + dg*4]);
                    f32x4 o;
                    o[0] = fmaf(f, carry4[0], bflo(hv[0]));
                    o[1] = fmaf(f, carry4[1], bfhi(hv[0]));
                    o[2] = fmaf(f, carry4[2], bflo(hv[1]));
                    o[3] = fmaf(f, carry4[3], bfhi(hv[1]));
                    *reinterpret_cast<f32x4*>(p + (size_t)q * 4 * ND) = o;
                    f *= lam4;
                }
            } else {
                float* p = ob + (size_t)(NT-1 - (tr0 + r0 + sr)) * ND + dg*4;
                #pragma unroll
                for (int q = 0; q < 8; ++q) {
                    u32x2 hv = *reinterpret_cast<const u32x2*>(
                        &xbuf[(r0 + q*4 + sr) * LDH + dg*4]);
                    f32x4 o;
                    o[0] = fmaf(f, carry4[0], bflo(hv[0]));
                    o[1] = fmaf(f, carry4[1], bfhi(hv[0]));
                    o[2] = fmaf(f, carry4[2], bflo(hv[1]));
                    o[3] = fmaf(f, carry4[3], bfhi(hv[1]));
                    *reinterpret_cast<f32x4*>(p - (size_t)q * 4 * ND) = o;
                    f *= lam4;
                }
            }
        }
        __syncthreads();   // xbuf/ends_lds/hprev_lds reuse safety
    }
}

extern "C" void kernel_launch(void* const* d_in, const int* in_sizes, int n_in,
                              void* d_out, int out_size, void* d_ws, size_t ws_size,
                              hipStream_t stream)
{
    const float* x  = (const float*)d_in[0];
    const float* Wf = (const float*)d_in[1];
    const float* bf = (const float*)d_in[2];
    const float* Wb = (const float*)d_in[3];
    const float* bb = (const float*)d_in[4];
    float* out = (float*)d_out;

    int*   flags = (int*)d_ws;                         // NSLOT ints (8 KiB)
    float* evals = (float*)((char*)d_ws + 16384);      // NSLOT*ND floats (512 KiB)

    Lams lams;
    const double delta = 13.0 / 7.0;   // log2(8192)/(C-1)
    for (int c = 0; c < 8; ++c)
        lams.v[c] = (float)(1.0 - pow(2.0, -(double)c * delta));

    // reset flags every launch (graph-replay safe, on-stream)
    hipMemsetAsync(flags, 0, NSLOT * 4, stream);

    dim3 grid(NBLK);   // 1024 blocks: (dir,c,b,kk), kk fastest — all resident
    k1_fused<<<grid, 512, 0, stream>>>(x, Wf, bf, Wb, bb, out, flags, evals, lams);
}